// Round 1
// baseline (2122.374 us; speedup 1.0000x reference)
//
#include <hip/hip_runtime.h>
#include <math.h>

#define BB 8
#define TT 32
#define DIN 768
#define DSAE 8192
#define KSEL 64

// ---------------------------------------------------------------------------
// K1: encoder partial GEMM. pre[r=t*8+b][s] += sum_{off in group, off<=t}
//     x[b][t-off][:] . Wenc[off][:][s]
// grid (DSAE/64, 4), block 256. Accumulate via fp32 atomicAdd into d_ws.
// Thread map: tg = tid>>3 (= t, so causal skip is uniform per 8-thread group,
// and per wave only one boundary wave diverges), cg = tid&7 (8 cols each).
// Register tile: 8 rows (b=0..7) x 8 cols = 64 fp32 accumulators.
// ---------------------------------------------------------------------------
__global__ __launch_bounds__(256) void enc_kernel(const float* __restrict__ x,
                                                  const float* __restrict__ Wenc,
                                                  float* __restrict__ pre) {
    // xs[t'][dl*8 + b], row stride 260 (pad +4: t' rows shift banks by 4 -> the
    // 8 distinct-t' lanes of a wave hit distinct bank quads on ds_read_b128)
    __shared__ float xs[TT][260];
    __shared__ float ws[32][64];   // [dl][sl]

    const int tid = threadIdx.x;
    const int tg  = tid >> 3;          // this thread's t (0..31)
    const int cg  = tid & 7;           // col group
    const int c0  = blockIdx.x * 64;   // s base
    const int offBase = blockIdx.y * 8;

    float acc[8][8];
#pragma unroll
    for (int i = 0; i < 8; ++i)
#pragma unroll
        for (int j = 0; j < 8; ++j) acc[i][j] = 0.f;

    for (int dc = 0; dc < DIN; dc += 32) {
        // stage x[b][t'][dc..dc+32) -> xs[t'][dl*8+b]  (8192 floats, f4 loads)
#pragma unroll
        for (int it = 0; it < 8; ++it) {
            const int lin4 = it * 256 + tid;   // 0..2047
            const int bt   = lin4 >> 3;        // b*32 + t'
            const int d4   = lin4 & 7;
            const float4 v = *(const float4*)(x + ((size_t)bt * DIN + dc + d4 * 4));
            const int b  = bt >> 5;
            const int tp = bt & 31;
            xs[tp][(d4 * 4 + 0) * 8 + b] = v.x;
            xs[tp][(d4 * 4 + 1) * 8 + b] = v.y;
            xs[tp][(d4 * 4 + 2) * 8 + b] = v.z;
            xs[tp][(d4 * 4 + 3) * 8 + b] = v.w;
        }
        for (int oi = 0; oi < 8; ++oi) {
            const int off = offBase + oi;
            // stage Wenc[off][dc+dl][c0+sl] -> ws[dl][sl] (2048 floats, f4)
#pragma unroll
            for (int it = 0; it < 2; ++it) {
                const int lin4 = it * 256 + tid;   // 0..511
                const int dl = lin4 >> 4;
                const int s4 = lin4 & 15;
                const float4 wv = *(const float4*)(
                    Wenc + ((size_t)(off * DIN + dc + dl) * DSAE + c0 + s4 * 4));
                *(float4*)&ws[dl][s4 * 4] = wv;
            }
            __syncthreads();   // xs (first oi) + ws ready
            if (tg >= off) {
                const float* xrow = &xs[tg - off][0];
#pragma unroll
                for (int dl = 0; dl < 32; ++dl) {
                    const float4 xa = *(const float4*)(xrow + dl * 8);
                    const float4 xb = *(const float4*)(xrow + dl * 8 + 4);
                    const float4 wa = *(const float4*)&ws[dl][cg * 8];
                    const float4 wb = *(const float4*)&ws[dl][cg * 8 + 4];
                    float xv[8] = {xa.x, xa.y, xa.z, xa.w, xb.x, xb.y, xb.z, xb.w};
                    float wv[8] = {wa.x, wa.y, wa.z, wa.w, wb.x, wb.y, wb.z, wb.w};
#pragma unroll
                    for (int i = 0; i < 8; ++i)
#pragma unroll
                        for (int j = 0; j < 8; ++j)
                            acc[i][j] = fmaf(xv[i], wv[j], acc[i][j]);
                }
            }
            __syncthreads();   // protect ws (and xs on last oi) before restage
        }
    }
#pragma unroll
    for (int b = 0; b < 8; ++b) {
        float* dst = pre + (size_t)(tg * 8 + b) * DSAE + c0 + cg * 8;
#pragma unroll
        for (int j = 0; j < 8; ++j) atomicAdd(dst + j, acc[b][j]);
    }
}

// ---------------------------------------------------------------------------
// K2: per position r=t*8+b: pre+=b_enc, top-64 (smallest-index tiebreak),
// z scatter, sparse decode x_hat = z@Wdec + b_dec, loss atomicAdd.
// grid 256, block 256.
// ---------------------------------------------------------------------------
__global__ __launch_bounds__(256) void topk_dec_kernel(
    const float* __restrict__ pre, const float* __restrict__ x,
    const float* __restrict__ Wdec, const float* __restrict__ benc,
    const float* __restrict__ bdec, float* __restrict__ out) {
    __shared__ float prebuf[DSAE];
    __shared__ float wvred[4];
    __shared__ int   wired[4];
    __shared__ float selv[KSEL];
    __shared__ int   seli[KSEL];
    __shared__ float zvs[KSEL];
    __shared__ float lred[4];

    const int tid = threadIdx.x;
    const int r = blockIdx.x;      // t*8 + b (K1 row order)
    const int t = r >> 3;
    const int b = r & 7;
    const int pos = b * TT + t;    // output-major position b*32+t

    // load pre row + b_enc
#pragma unroll
    for (int it = 0; it < 8; ++it) {
        const int s4 = it * 256 + tid;
        float4 v  = *(const float4*)(pre + (size_t)r * DSAE + s4 * 4);
        const float4 be = *(const float4*)(benc + s4 * 4);
        v.x += be.x; v.y += be.y; v.z += be.z; v.w += be.w;
        *(float4*)&prebuf[s4 * 4] = v;
    }
    __syncthreads();

    // iterative top-64: each thread owns 32 contiguous s, caches local argmax,
    // rescans only when its cached max was consumed.
    float lv = -INFINITY;
    int   li = 0x7fffffff;
    bool  need = true;
    for (int k = 0; k < KSEL; ++k) {
        if (need) {
            lv = -INFINITY; li = 0x7fffffff;
            const int s0 = tid * 32;
            for (int i = 0; i < 32; ++i) {
                const float v = prebuf[s0 + i];
                if (v > lv) { lv = v; li = s0 + i; }   // '>' keeps smallest idx
            }
            need = false;
        }
        float rv = lv; int ri = li;
#pragma unroll
        for (int sh = 32; sh >= 1; sh >>= 1) {
            const float ov = __shfl_down(rv, sh);
            const int   oi = __shfl_down(ri, sh);
            if (ov > rv || (ov == rv && oi < ri)) { rv = ov; ri = oi; }
        }
        if ((tid & 63) == 0) { wvred[tid >> 6] = rv; wired[tid >> 6] = ri; }
        __syncthreads();
        if (tid == 0) {
            float bv = wvred[0]; int bi = wired[0];
            for (int w = 1; w < 4; ++w)
                if (wvred[w] > bv || (wvred[w] == bv && wired[w] < bi)) {
                    bv = wvred[w]; bi = wired[w];
                }
            selv[k] = bv; seli[k] = bi;
            prebuf[bi] = -INFINITY;
        }
        __syncthreads();
        if (seli[k] == li) need = true;
    }

    if (tid < KSEL) zvs[tid] = fmaxf(selv[tid], 0.f);
    __syncthreads();

    // z: dense zeros then scatter (ordered by __syncthreads)
    float* zout = out + 1 + (size_t)BB * TT * DIN + (size_t)pos * DSAE;
    const float4 z4 = make_float4(0.f, 0.f, 0.f, 0.f);
#pragma unroll
    for (int it = 0; it < 8; ++it) {
        const int s4 = it * 256 + tid;
        *(float4*)&zout[s4 * 4] = z4;
    }
    __syncthreads();
    if (tid < KSEL) zout[seli[tid]] = zvs[tid];

    // x_hat + loss
    const float* xrow = x + (size_t)pos * DIN;
    float* xhout = out + 1 + (size_t)pos * DIN;
    float lsum = 0.f;
#pragma unroll
    for (int j = 0; j < 3; ++j) {
        const int d = j * 256 + tid;
        float a = bdec[d];
        for (int k = 0; k < KSEL; ++k)
            a = fmaf(zvs[k], Wdec[(size_t)seli[k] * DIN + d], a);
        xhout[d] = a;
        const float df = a - xrow[d];
        lsum = fmaf(df, df, lsum);
    }
#pragma unroll
    for (int sh = 32; sh >= 1; sh >>= 1) lsum += __shfl_down(lsum, sh);
    if ((tid & 63) == 0) lred[tid >> 6] = lsum;
    __syncthreads();
    if (tid == 0)
        atomicAdd(out, (lred[0] + lred[1] + lred[2] + lred[3]) * (1.0f / (BB * TT)));
}

extern "C" void kernel_launch(void* const* d_in, const int* in_sizes, int n_in,
                              void* d_out, int out_size, void* d_ws, size_t ws_size,
                              hipStream_t stream) {
    const float* x    = (const float*)d_in[0];
    const float* Wenc = (const float*)d_in[1];
    const float* Wdec = (const float*)d_in[2];
    const float* benc = (const float*)d_in[3];
    const float* bdec = (const float*)d_in[4];
    float* out = (float*)d_out;
    float* pre = (float*)d_ws;   // 256*8192 fp32 = 8 MB

    hipMemsetAsync(pre, 0, (size_t)BB * TT * DSAE * sizeof(float), stream);
    hipMemsetAsync(d_out, 0, sizeof(float), stream);  // loss accumulator

    enc_kernel<<<dim3(DSAE / 64, 4), 256, 0, stream>>>(x, Wenc, pre);
    topk_dec_kernel<<<256, 256, 0, stream>>>(pre, x, Wdec, benc, bdec, out);
}

// Round 2
// 1151.638 us; speedup vs baseline: 1.8429x; 1.8429x over previous
//
#include <hip/hip_runtime.h>
#include <math.h>

#define DIN 768
#define DSAE 8192
#define RPOS 256     // B*T rows, r = t*8 + b
#define KSEL 64
#define NG 4
#define PRE_STRIDE (RPOS * DSAE)
#define CAP 1024

typedef _Float16 f16x8 __attribute__((ext_vector_type(8)));
typedef float f32x4 __attribute__((ext_vector_type(4)));

#define XS_STRIDE 40   // f16 elements per row (32 + pad, keeps 16B align + bank spread)
#define WS_STRIDE 40

// ---------------------------------------------------------------------------
// K1: MFMA encoder. pre_g[r][s] = sum_{off in group g} sum_d x[b][t-off][d] W[off][d][s]
// fp16 hi/lo split: w = wh + wl/2048, x = xh + xl/2048 (split exact in fp32).
// accA += xh*wh ; accB += xh*wl' + xl'*wh (lo planes pre-scaled by 2^11)
// pre = accA + accB/2048.  Error ~2^-21 rel — below fp32-reorder noise.
// grid (128 col-stripes of 64, 4 off-groups), block 256 (4 waves x 64 rows).
// offs interleaved: off = g + 4*oi  (balances causal work across groups).
// ---------------------------------------------------------------------------
__global__ __launch_bounds__(256, 2) void enc_kernel(
    const float* __restrict__ x, const float* __restrict__ Wenc,
    float* __restrict__ pre, int nbuf) {
  // xs rows 0..7 = zeros (odd-off boundary pad); row 8+rx = x row rx = r - 8*off
  __shared__ __align__(16) _Float16 xsh[264 * XS_STRIDE];
  __shared__ __align__(16) _Float16 xsl[264 * XS_STRIDE];
  __shared__ __align__(16) _Float16 wsh[64 * WS_STRIDE];  // [s][d], chunk-swizzled
  __shared__ __align__(16) _Float16 wsl[64 * WS_STRIDE];

  const int tid = threadIdx.x;
  const int lane = tid & 63;
  const int wv = tid >> 6;
  const int g = blockIdx.y;
  const int c0 = blockIdx.x * 64;
  float* preOut = pre + (size_t)(g % nbuf) * PRE_STRIDE;
  const bool atomicMode = (nbuf < NG);

  {  // zero pad rows (8 rows * 40 f16 = 160 dwords per plane)
    uint32_t* ph = (uint32_t*)xsh;
    uint32_t* pl = (uint32_t*)xsl;
    if (tid < 160) { ph[tid] = 0u; pl[tid] = 0u; }
  }

  f32x4 accA[4][4], accB[4][4];
  const f32x4 zero4 = {0.f, 0.f, 0.f, 0.f};
#pragma unroll
  for (int i = 0; i < 4; ++i)
#pragma unroll
    for (int j = 0; j < 4; ++j) { accA[i][j] = zero4; accB[i][j] = zero4; }

  const int dl = tid >> 3;  // W stage: d 0..31
  const int sq = tid & 7;   // W stage: 8 s each

  float4 wA, wB;  // prefetched W tile regs
  {
    const float* p = Wenc + ((size_t)(g * DIN + dl)) * DSAE + c0 + sq * 8;
    wA = *(const float4*)p;
    wB = *(const float4*)(p + 4);
  }

#pragma unroll 1
  for (int it = 0; it < 192; ++it) {
    const int dc = (it >> 3) << 5;
    const int oi = it & 7;
    const int off = g + (oi << 2);

    if (oi == 0) {
      // stage x: thread owns row r=tid, 32 d. x row index = b*32 + t
      const int r = tid;
      const int xr = ((r & 7) << 5) + (r >> 3);
      const float* gp = x + (size_t)xr * DIN + dc;
      float4 xv4[8];
#pragma unroll
      for (int q = 0; q < 8; ++q) xv4[q] = *(const float4*)(gp + q * 4);
      const int row = 8 + r;
      const int sw = ((row >> 2) ^ row) & 3;
#pragma unroll
      for (int kg = 0; kg < 4; ++kg) {
        float xv[8] = {xv4[2*kg].x, xv4[2*kg].y, xv4[2*kg].z, xv4[2*kg].w,
                       xv4[2*kg+1].x, xv4[2*kg+1].y, xv4[2*kg+1].z, xv4[2*kg+1].w};
        f16x8 h, l;
#pragma unroll
        for (int e = 0; e < 8; ++e) {
          float xx = xv[e];
          _Float16 xh = (_Float16)xx;
          h[e] = xh;
          l[e] = (_Float16)((xx - (float)xh) * 2048.f);
        }
        *(f16x8*)&xsh[row * XS_STRIDE + ((kg ^ sw) << 3)] = h;
        *(f16x8*)&xsl[row * XS_STRIDE + ((kg ^ sw) << 3)] = l;
      }
    }

    {  // split + transpose-write current W tile
      float wvv[8] = {wA.x, wA.y, wA.z, wA.w, wB.x, wB.y, wB.z, wB.w};
#pragma unroll
      for (int j = 0; j < 8; ++j) {
        const int s = sq * 8 + j;
        const int colidx = dl ^ (((s >> 2) & 3) << 3);
        float ww = wvv[j];
        _Float16 wh = (_Float16)ww;
        wsh[s * WS_STRIDE + colidx] = wh;
        wsl[s * WS_STRIDE + colidx] = (_Float16)((ww - (float)wh) * 2048.f);
      }
    }
    {  // prefetch next W tile (clamped redundant on last iter)
      const int it2 = (it < 191) ? it + 1 : it;
      const int dcn = (it2 >> 3) << 5;
      const int offn = g + ((it2 & 7) << 2);
      const float* p = Wenc + ((size_t)(offn * DIN + dcn + dl)) * DSAE + c0 + sq * 8;
      wA = *(const float4*)p;
      wB = *(const float4*)(p + 4);
    }
    __syncthreads();

    if (off <= wv * 8 + 7) {  // wave has at least one active row-tile
      const int m = lane & 15;
      const int kg = lane >> 4;
      bool act[4];
      f16x8 ah[4], al[4];
#pragma unroll
      for (int rt = 0; rt < 4; ++rt) {
        act[rt] = (off <= wv * 8 + 2 * rt + 1);
        if (act[rt]) {
          const int row = (wv * 4 + rt) * 16 + m - 8 * off + 8;
          const int sw = ((row >> 2) ^ row) & 3;
          ah[rt] = *(const f16x8*)&xsh[row * XS_STRIDE + ((kg ^ sw) << 3)];
          al[rt] = *(const f16x8*)&xsl[row * XS_STRIDE + ((kg ^ sw) << 3)];
        }
      }
#pragma unroll
      for (int ct = 0; ct < 4; ++ct) {
        const int sL = ct * 16 + m;
        const int cidx = (kg ^ ((m >> 2) & 3)) << 3;
        const f16x8 bh = *(const f16x8*)&wsh[sL * WS_STRIDE + cidx];
        const f16x8 bl = *(const f16x8*)&wsl[sL * WS_STRIDE + cidx];
#pragma unroll
        for (int rt = 0; rt < 4; ++rt) {
          if (act[rt]) {
            accA[rt][ct] = __builtin_amdgcn_mfma_f32_16x16x32_f16(ah[rt], bh, accA[rt][ct], 0, 0, 0);
            accB[rt][ct] = __builtin_amdgcn_mfma_f32_16x16x32_f16(ah[rt], bl, accB[rt][ct], 0, 0, 0);
            accB[rt][ct] = __builtin_amdgcn_mfma_f32_16x16x32_f16(al[rt], bh, accB[rt][ct], 0, 0, 0);
          }
        }
      }
    }
    __syncthreads();
  }

  // epilogue: C/D layout col=lane&15, row=(lane>>4)*4+reg
  const int quad = lane >> 4;
  const int col = lane & 15;
#pragma unroll
  for (int rt = 0; rt < 4; ++rt)
#pragma unroll
    for (int ct = 0; ct < 4; ++ct)
#pragma unroll
      for (int reg = 0; reg < 4; ++reg) {
        const float v = accA[rt][ct][reg] + accB[rt][ct][reg] * (1.f / 2048.f);
        const int rr = (wv * 4 + rt) * 16 + quad * 4 + reg;
        const size_t idx = (size_t)rr * DSAE + c0 + ct * 16 + col;
        if (atomicMode) atomicAdd(&preOut[idx], v);
        else preOut[idx] = v;
      }
}

// ---------------------------------------------------------------------------
// K2: per position: sum partials + b_enc, radix-select top-64 (exact, with
// smallest-index tiebreak), z scatter, sparse decode, loss. grid 256, block 256.
// ---------------------------------------------------------------------------
__global__ __launch_bounds__(256) void topk_dec_kernel(
    const float* __restrict__ pre, const float* __restrict__ x,
    const float* __restrict__ Wdec, const float* __restrict__ benc,
    const float* __restrict__ bdec, float* __restrict__ out, int nbuf) {
  __shared__ float prebuf[DSAE];
  __shared__ uint32_t hist[4096];
  __shared__ uint32_t sb[256];
  __shared__ uint32_t candU[CAP];
  __shared__ int candS[CAP];
  __shared__ int seli[KSEL];
  __shared__ float zvs[KSEL];
  __shared__ int shB, shK, cntSel, cntCand;
  __shared__ float lred[4];

  const int tid = threadIdx.x;
  const int r = blockIdx.x;
  const int t = r >> 3, b = r & 7;
  const int pos = b * 32 + t;

#pragma unroll
  for (int it = 0; it < 8; ++it) {
    const int s4 = it * 256 + tid;
    float4 v = *(const float4*)(benc + s4 * 4);
    for (int q = 0; q < nbuf; ++q) {
      const float4 p4 = *(const float4*)(pre + (size_t)q * PRE_STRIDE + (size_t)r * DSAE + s4 * 4);
      v.x += p4.x; v.y += p4.y; v.z += p4.z; v.w += p4.w;
    }
    *(float4*)&prebuf[s4 * 4] = v;
  }
  for (int i = tid; i < 4096; i += 256) hist[i] = 0u;
  if (tid == 0) { cntSel = 0; cntCand = 0; }
  __syncthreads();

  // histogram of top-12 sortable bits (bin ascending = value ascending)
#pragma unroll
  for (int j = 0; j < 32; ++j) {
    const int s = j * 256 + tid;
    const uint32_t bits = __float_as_uint(prebuf[s]);
    const uint32_t u = bits ^ ((uint32_t)((int)bits >> 31) | 0x80000000u);
    atomicAdd(&hist[u >> 20], 1u);
  }
  __syncthreads();

  uint32_t segSum = 0;
  for (int q = 0; q < 16; ++q) segSum += hist[tid * 16 + q];
  sb[tid] = segSum;
  __syncthreads();
  for (int s = 1; s < 256; s <<= 1) {  // inclusive suffix scan
    const uint32_t tt = (tid + s < 256) ? sb[tid + s] : 0u;
    __syncthreads();
    sb[tid] += tt;
    __syncthreads();
  }
  {
    const uint32_t incl = sb[tid];
    const uint32_t strictAbove = incl - segSum;
    if (incl >= KSEL && strictAbove < KSEL) {  // crossing segment (unique)
      int cum = (int)strictAbove;
      for (int bb = tid * 16 + 15; bb >= tid * 16; --bb) {
        const int cnt = (int)hist[bb];
        if (cum + cnt >= KSEL) { shB = bb; shK = KSEL - cum; break; }
        cum += cnt;
      }
    }
  }
  __syncthreads();
  const int Bbin = shB;
  const int kneed = shK;

  // collect definite selections + boundary-bin candidates
#pragma unroll
  for (int j = 0; j < 32; ++j) {
    const int s = j * 256 + tid;
    const float v = prebuf[s];
    const uint32_t bits = __float_as_uint(v);
    const uint32_t u = bits ^ ((uint32_t)((int)bits >> 31) | 0x80000000u);
    const int bin = (int)(u >> 20);
    if (bin > Bbin) {
      const int p = atomicAdd(&cntSel, 1);
      seli[p] = s;
      zvs[p] = fmaxf(v, 0.f);
    } else if (bin == Bbin) {
      const int p = atomicAdd(&cntCand, 1);
      if (p < CAP) { candU[p] = u; candS[p] = s; }
    }
  }
  __syncthreads();
  int c = cntCand;
  if (c > CAP) c = CAP;
  for (int j = tid; j < c; j += 256) {  // exact rank among candidates
    const uint32_t uj = candU[j];
    const int sj = candS[j];
    int rank = 0;
    for (int i = 0; i < c; ++i) {
      const uint32_t ui = candU[i];
      rank += (ui > uj) || (ui == uj && candS[i] < sj);
    }
    if (rank < kneed) {
      const int p = atomicAdd(&cntSel, 1);
      seli[p] = sj;
      zvs[p] = fmaxf(prebuf[sj], 0.f);
    }
  }
  __syncthreads();

  // z: zero then scatter (barrier orders block-internal global writes)
  float* zout = out + 1 + (size_t)RPOS * DIN + (size_t)pos * DSAE;
  const float4 z4 = {0.f, 0.f, 0.f, 0.f};
#pragma unroll
  for (int it = 0; it < 8; ++it) *(float4*)&zout[(it * 256 + tid) * 4] = z4;
  __syncthreads();
  if (tid < KSEL) zout[seli[tid]] = zvs[tid];

  // x_hat + loss
  const float* xrow = x + (size_t)pos * DIN;
  float* xhout = out + 1 + (size_t)pos * DIN;
  float lsum = 0.f;
#pragma unroll
  for (int j = 0; j < 3; ++j) {
    const int d = j * 256 + tid;
    float a = bdec[d];
    for (int k = 0; k < KSEL; ++k)
      a = fmaf(zvs[k], Wdec[(size_t)seli[k] * DIN + d], a);
    xhout[d] = a;
    const float df = a - xrow[d];
    lsum = fmaf(df, df, lsum);
  }
#pragma unroll
  for (int sh = 32; sh >= 1; sh >>= 1) lsum += __shfl_down(lsum, sh);
  if ((tid & 63) == 0) lred[tid >> 6] = lsum;
  __syncthreads();
  if (tid == 0)
    atomicAdd(out, (lred[0] + lred[1] + lred[2] + lred[3]) * (1.0f / RPOS));
}

extern "C" void kernel_launch(void* const* d_in, const int* in_sizes, int n_in,
                              void* d_out, int out_size, void* d_ws, size_t ws_size,
                              hipStream_t stream) {
  const float* x    = (const float*)d_in[0];
  const float* Wenc = (const float*)d_in[1];
  const float* Wdec = (const float*)d_in[2];
  const float* benc = (const float*)d_in[3];
  const float* bdec = (const float*)d_in[4];
  float* out = (float*)d_out;
  float* pre = (float*)d_ws;

  int nbuf = (int)(ws_size / ((size_t)PRE_STRIDE * sizeof(float)));
  if (nbuf > NG) nbuf = NG;
  if (nbuf < 1) nbuf = 1;
  if (nbuf < NG)  // atomic fallback needs zeroed partials
    hipMemsetAsync(pre, 0, (size_t)nbuf * PRE_STRIDE * sizeof(float), stream);
  hipMemsetAsync(d_out, 0, sizeof(float), stream);  // loss accumulator

  enc_kernel<<<dim3(DSAE / 64, NG), 256, 0, stream>>>(x, Wenc, pre, nbuf);
  topk_dec_kernel<<<RPOS, 256, 0, stream>>>(pre, x, Wdec, benc, bdec, out, nbuf);
}